// Round 1
// baseline (1303.266 us; speedup 1.0000x reference)
//
#include <hip/hip_runtime.h>
#include <math.h>

#define NNODE_HINT 50000

// ---------------------------------------------------------------- CSR build
__global__ __launch_bounds__(256) void count_kernel(const int* __restrict__ dst,
                                                    int* __restrict__ deg, int E) {
    int e = blockIdx.x * 256 + threadIdx.x;
    if (e < E) atomicAdd(&deg[dst[e]], 1);
}

__global__ __launch_bounds__(1024) void exscan_kernel(const int* __restrict__ deg,
                                                      int* __restrict__ rowptr,
                                                      int* __restrict__ cursor, int n) {
    __shared__ int sh[1024];
    __shared__ int carry;
    if (threadIdx.x == 0) carry = 0;
    __syncthreads();
    for (int base = 0; base < n; base += 1024) {
        int i = base + (int)threadIdx.x;
        int v = (i < n) ? deg[i] : 0;
        sh[threadIdx.x] = v;
        __syncthreads();
        for (int off = 1; off < 1024; off <<= 1) {
            int t = (threadIdx.x >= (unsigned)off) ? sh[threadIdx.x - off] : 0;
            __syncthreads();
            sh[threadIdx.x] += t;
            __syncthreads();
        }
        int incl = sh[threadIdx.x];
        int excl = incl - v;
        if (i < n) { rowptr[i] = carry + excl; cursor[i] = carry + excl; }
        __syncthreads();
        if (threadIdx.x == 1023) carry += incl;
        __syncthreads();
    }
    if (threadIdx.x == 0) rowptr[n] = carry;
}

__global__ __launch_bounds__(256) void scatter_kernel(const int* __restrict__ src,
                                                      const int* __restrict__ dst,
                                                      int* __restrict__ cursor,
                                                      int2* __restrict__ csr, int E) {
    int e = blockIdx.x * 256 + threadIdx.x;
    if (e < E) {
        int d = dst[e];
        int pos = atomicAdd(&cursor[d], 1);
        csr[pos] = make_int2(src[e], e);
    }
}

// ------------------------------------------------- xl = x@Wl+bl, xr = x@Wr
#define GROWS 32
__global__ __launch_bounds__(256) void gemm2_kernel(const float* __restrict__ xin, int K,
                                                    const float* __restrict__ Wl,
                                                    const float* __restrict__ bl,
                                                    const float* __restrict__ Wr,
                                                    float* __restrict__ xl,
                                                    float* __restrict__ xr, int Nn) {
    __shared__ __align__(16) float sh[GROWS][64];
    int j = threadIdx.x;            // 0..255 output column
    int n0 = blockIdx.x * GROWS;
    for (int t = threadIdx.x; t < GROWS * K; t += 256) {
        int r = t / K, k = t - r * K;
        int n = n0 + r;
        sh[r][k] = (n < Nn) ? xin[(size_t)n * K + k] : 0.f;
    }
    __syncthreads();
    float accl[GROWS], accr[GROWS];
    float b = bl[j];
#pragma unroll
    for (int r = 0; r < GROWS; r++) { accl[r] = b; accr[r] = 0.f; }
    if (K == 64) {
        for (int k4 = 0; k4 < 16; k4++) {
            int k = k4 * 4;
            float wl0 = Wl[(k + 0) * 256 + j], wl1 = Wl[(k + 1) * 256 + j];
            float wl2 = Wl[(k + 2) * 256 + j], wl3 = Wl[(k + 3) * 256 + j];
            float wr0 = Wr[(k + 0) * 256 + j], wr1 = Wr[(k + 1) * 256 + j];
            float wr2 = Wr[(k + 2) * 256 + j], wr3 = Wr[(k + 3) * 256 + j];
#pragma unroll
            for (int r = 0; r < GROWS; r++) {
                float4 h4 = *(const float4*)&sh[r][k];
                accl[r] += h4.x * wl0 + h4.y * wl1 + h4.z * wl2 + h4.w * wl3;
                accr[r] += h4.x * wr0 + h4.y * wr1 + h4.z * wr2 + h4.w * wr3;
            }
        }
    } else {
        for (int k = 0; k < K; k++) {
            float wl = Wl[k * 256 + j], wr = Wr[k * 256 + j];
#pragma unroll
            for (int r = 0; r < GROWS; r++) { accl[r] += sh[r][k] * wl; accr[r] += sh[r][k] * wr; }
        }
    }
    for (int r = 0; r < GROWS; r++) {
        int n = n0 + r;
        if (n < Nn) { xl[(size_t)n * 256 + j] = accl[r]; xr[(size_t)n * 256 + j] = accr[r]; }
    }
}

// --------------------------- fused GATv2: attention + softmax + aggregate +
// --------------------------- head-mean + bias + BN + ELU + residual
__global__ __launch_bounds__(256) void gat_kernel(const float* __restrict__ xl,
                                                  const float* __restrict__ xr,
                                                  const float* __restrict__ We,   // [3,256]
                                                  const float* __restrict__ att,  // [256]
                                                  const float* __restrict__ bias, // [64]
                                                  const float* __restrict__ bng,
                                                  const float* __restrict__ bnb,
                                                  const float* __restrict__ bnm,
                                                  const float* __restrict__ bnv,
                                                  const float* __restrict__ ea,   // [E,3]
                                                  const int* __restrict__ rowptr,
                                                  const int2* __restrict__ csr,
                                                  float* __restrict__ hout,       // [N,64]
                                                  const float* __restrict__ hres, // [N,64] or null
                                                  int Nn) {
    int d = blockIdx.x;
    int tid = threadIdx.x;       // (h = tid>>6, c = tid&63)
    int lane = tid & 63;
    __shared__ float sWe[768];
    __shared__ float sred[4][64];
    sWe[tid] = We[tid];
    sWe[256 + tid] = We[256 + tid];
    sWe[512 + tid] = We[512 + tid];
    __syncthreads();

    float xrv = xr[(size_t)d * 256 + tid];
    float attv = att[tid];
    int beg = rowptr[d], end = rowptr[d + 1];

    float m_run = -INFINITY, l_run = 0.f, acc = 0.f;
    for (int i = beg; i < end; i++) {
        int2 se = csr[i];
        float ea0 = ea[(size_t)se.y * 3 + 0];
        float ea1 = ea[(size_t)se.y * 3 + 1];
        float ea2 = ea[(size_t)se.y * 3 + 2];
        float eev = ea0 * sWe[tid] + ea1 * sWe[256 + tid] + ea2 * sWe[512 + tid];
        float xlv = xl[(size_t)se.x * 256 + tid];
        float mv = xlv + xrv + eev;
        float p = (mv > 0.f ? mv : 0.2f * mv) * attv;
#pragma unroll
        for (int off = 32; off; off >>= 1) p += __shfl_xor(p, off);
        // p is now s[e,h], identical across the wave
        float mnew = fmaxf(m_run, p);
        float sc = __expf(m_run - mnew);  // exp(-inf)=0 on first edge
        float wv = __expf(p - mnew);
        acc = acc * sc + wv * xlv;
        l_run = l_run * sc + wv;
        m_run = mnew;
    }
    float outv = (end > beg) ? acc / l_run : 0.f;
    sred[tid >> 6][lane] = outv;
    __syncthreads();
    if (tid < 64) {
        float v = 0.25f * (sred[0][tid] + sred[1][tid] + sred[2][tid] + sred[3][tid]) + bias[tid];
        v = (v - bnm[tid]) * (bng[tid] * rsqrtf(bnv[tid] + 1e-5f)) + bnb[tid];
        v = v > 0.f ? v : expm1f(v);
        if (hres) v += hres[(size_t)d * 64 + tid];
        hout[(size_t)d * 64 + tid] = v;
    }
}

// ---------------------------------------------------------------- pooling
__global__ __launch_bounds__(256) void pool_kernel(const float* __restrict__ h,
                                                   const int* __restrict__ batch,
                                                   float* __restrict__ pooled,
                                                   int* __restrict__ cnt, int Nn) {
    int idx = blockIdx.x * 256 + threadIdx.x;
    int n = idx >> 6, c = idx & 63;
    if (n < Nn) {
        int g = batch[n];
        atomicAdd(&pooled[(size_t)g * 64 + c], h[(size_t)n * 64 + c]);
        if (c == 0) atomicAdd(&cnt[g], 1);
    }
}

// ---------------------------------------------------------------- MLP head
__global__ __launch_bounds__(64) void head_kernel(const float* __restrict__ pooled,
                                                  const int* __restrict__ cnt,
                                                  const float* __restrict__ Wo1,
                                                  const float* __restrict__ bo1,
                                                  const float* __restrict__ Wo2,
                                                  const float* __restrict__ bo2,
                                                  float* __restrict__ out, int Gg) {
    int g = blockIdx.x;
    int t = threadIdx.x;
    __shared__ float sp[64];
    float c = fmaxf((float)cnt[g], 1.f);
    sp[t] = pooled[(size_t)g * 64 + t] / c;
    __syncthreads();
    float hid = 0.f;
    if (t < 32) {
        hid = bo1[t];
        for (int k = 0; k < 64; k++) hid += sp[k] * Wo1[k * 32 + t];
        hid = hid > 0.f ? hid : expm1f(hid);
        hid *= Wo2[t];
    }
#pragma unroll
    for (int off = 32; off; off >>= 1) hid += __shfl_xor(hid, off);
    if (t == 0) out[g] = hid + bo2[0];
}

extern "C" void kernel_launch(void* const* d_in, const int* in_sizes, int n_in,
                              void* d_out, int out_size, void* d_ws, size_t ws_size,
                              hipStream_t stream) {
    const float* x   = (const float*)d_in[0];
    const int*   ei  = (const int*)d_in[1];
    const int*   bat = (const int*)d_in[2];
    const float* ea  = (const float*)d_in[3];
    const float* W0l = (const float*)d_in[4];
    const float* b0l = (const float*)d_in[5];
    const float* W0r = (const float*)d_in[6];
    const float* W0e = (const float*)d_in[7];
    const float* a0  = (const float*)d_in[8];
    const float* c0  = (const float*)d_in[9];
    const float* Wl  = (const float*)d_in[10];
    const float* bl  = (const float*)d_in[11];
    const float* Wr  = (const float*)d_in[12];
    const float* We  = (const float*)d_in[13];
    const float* a   = (const float*)d_in[14];
    const float* cb  = (const float*)d_in[15];
    const float* bng = (const float*)d_in[16];
    const float* bnb = (const float*)d_in[17];
    const float* bnm = (const float*)d_in[18];
    const float* bnv = (const float*)d_in[19];
    const float* Wo1 = (const float*)d_in[20];
    const float* bo1 = (const float*)d_in[21];
    const float* Wo2 = (const float*)d_in[22];
    const float* bo2 = (const float*)d_in[23];

    int Nn = in_sizes[2];
    int Ee = in_sizes[1] / 2;
    int Gg = out_size;
    const int* srcv = ei;
    const int* dstv = ei + Ee;

    char* w = (char*)d_ws;
    auto alloc = [&](size_t bytes) {
        char* p = w;
        w += (bytes + 255) & ~(size_t)255;
        return p;
    };
    float* xlb    = (float*)alloc((size_t)Nn * 256 * 4);
    float* xrb    = (float*)alloc((size_t)Nn * 256 * 4);
    float* hbuf   = (float*)alloc((size_t)Nn * 64 * 4);
    int*   deg    = (int*)alloc((size_t)Nn * 4);
    int*   rowptr = (int*)alloc((size_t)(Nn + 1) * 4);
    int*   cursor = (int*)alloc((size_t)Nn * 4);
    int2*  csr    = (int2*)alloc((size_t)Ee * 8);
    float* pooled = (float*)alloc((size_t)Gg * 64 * 4);
    int*   cnt    = (int*)alloc((size_t)Gg * 4);

    // CSR build (every call — deterministic)
    hipMemsetAsync(deg, 0, (size_t)Nn * 4, stream);
    count_kernel<<<(Ee + 255) / 256, 256, 0, stream>>>(dstv, deg, Ee);
    exscan_kernel<<<1, 1024, 0, stream>>>(deg, rowptr, cursor, Nn);
    scatter_kernel<<<(Ee + 255) / 256, 256, 0, stream>>>(srcv, dstv, cursor, csr, Ee);

    // layer 0 (K=9)
    gemm2_kernel<<<(Nn + GROWS - 1) / GROWS, 256, 0, stream>>>(x, 9, W0l, b0l, W0r, xlb, xrb, Nn);
    gat_kernel<<<Nn, 256, 0, stream>>>(xlb, xrb, W0e, a0, c0,
                                       bng, bnb, bnm, bnv,
                                       ea, rowptr, csr, hbuf, nullptr, Nn);
    // 3 residual layers (K=64)
    for (int i = 0; i < 3; i++) {
        gemm2_kernel<<<(Nn + GROWS - 1) / GROWS, 256, 0, stream>>>(
            hbuf, 64, Wl + (size_t)i * 64 * 256, bl + (size_t)i * 256,
            Wr + (size_t)i * 64 * 256, xlb, xrb, Nn);
        gat_kernel<<<Nn, 256, 0, stream>>>(
            xlb, xrb, We + (size_t)i * 768, a + (size_t)i * 256, cb + (size_t)i * 64,
            bng + (size_t)(i + 1) * 64, bnb + (size_t)(i + 1) * 64,
            bnm + (size_t)(i + 1) * 64, bnv + (size_t)(i + 1) * 64,
            ea, rowptr, csr, hbuf, hbuf, Nn);
    }

    // global mean pool + head
    hipMemsetAsync(pooled, 0, (size_t)Gg * 64 * 4, stream);
    hipMemsetAsync(cnt, 0, (size_t)Gg * 4, stream);
    pool_kernel<<<((size_t)Nn * 64 + 255) / 256, 256, 0, stream>>>(hbuf, bat, pooled, cnt, Nn);
    head_kernel<<<Gg, 64, 0, stream>>>(pooled, cnt, Wo1, bo1, Wo2, bo2, (float*)d_out, Gg);
}

// Round 2
// 913.418 us; speedup vs baseline: 1.4268x; 1.4268x over previous
//
#include <hip/hip_runtime.h>
#include <math.h>

// ---------------------------------------------------------------- CSR build
__global__ __launch_bounds__(256) void count_kernel(const int* __restrict__ dst,
                                                    int* __restrict__ deg, int E) {
    int e = blockIdx.x * 256 + threadIdx.x;
    if (e < E) atomicAdd(&deg[dst[e]], 1);
}

#define SCAN_TPB 256
#define SCAN_VPT 4
#define SCAN_ELEMS (SCAN_TPB * SCAN_VPT)  // 1024

__global__ __launch_bounds__(256) void scan_phase1(const int* __restrict__ deg,
                                                   int* __restrict__ bsum, int n) {
    __shared__ int sh[SCAN_TPB];
    int base = blockIdx.x * SCAN_ELEMS + threadIdx.x * SCAN_VPT;
    int s = 0;
#pragma unroll
    for (int j = 0; j < SCAN_VPT; j++) { int i = base + j; if (i < n) s += deg[i]; }
    sh[threadIdx.x] = s;
    __syncthreads();
    for (int off = 128; off; off >>= 1) {
        if (threadIdx.x < (unsigned)off) sh[threadIdx.x] += sh[threadIdx.x + off];
        __syncthreads();
    }
    if (threadIdx.x == 0) bsum[blockIdx.x] = sh[0];
}

// single block: exclusive scan of bsum (nb <= 256), writes rowptr[n]=total
__global__ __launch_bounds__(256) void scan_phase2(int* __restrict__ bsum, int nb,
                                                   int* __restrict__ rowptr, int n) {
    __shared__ int sh[256];
    int v = (threadIdx.x < (unsigned)nb) ? bsum[threadIdx.x] : 0;
    sh[threadIdx.x] = v;
    __syncthreads();
    for (int off = 1; off < 256; off <<= 1) {
        int t = (threadIdx.x >= (unsigned)off) ? sh[threadIdx.x - off] : 0;
        __syncthreads();
        sh[threadIdx.x] += t;
        __syncthreads();
    }
    if (threadIdx.x < (unsigned)nb) bsum[threadIdx.x] = sh[threadIdx.x] - v;  // exclusive
    if (threadIdx.x == 0) rowptr[n] = sh[255];                                // total
}

__global__ __launch_bounds__(256) void scan_phase3(const int* __restrict__ deg,
                                                   const int* __restrict__ bsum,
                                                   int* __restrict__ rowptr,
                                                   int* __restrict__ cursor, int n) {
    __shared__ int sh[SCAN_TPB];
    int tid = threadIdx.x;
    int base = blockIdx.x * SCAN_ELEMS + tid * SCAN_VPT;
    int v[SCAN_VPT];
    int s = 0;
#pragma unroll
    for (int j = 0; j < SCAN_VPT; j++) { int i = base + j; v[j] = (i < n) ? deg[i] : 0; s += v[j]; }
    sh[tid] = s;
    __syncthreads();
    for (int off = 1; off < SCAN_TPB; off <<= 1) {
        int t = (tid >= off) ? sh[tid - off] : 0;
        __syncthreads();
        sh[tid] += t;
        __syncthreads();
    }
    int ex = sh[tid] - s + bsum[blockIdx.x];
#pragma unroll
    for (int j = 0; j < SCAN_VPT; j++) {
        int i = base + j;
        if (i < n) { rowptr[i] = ex; cursor[i] = ex; ex += v[j]; }
    }
}

__global__ __launch_bounds__(256) void scatter_kernel(const int* __restrict__ src,
                                                      const int* __restrict__ dst,
                                                      int* __restrict__ cursor,
                                                      int2* __restrict__ csr, int E) {
    int e = blockIdx.x * 256 + threadIdx.x;
    if (e < E) {
        int d = dst[e];
        int pos = atomicAdd(&cursor[d], 1);
        csr[pos] = make_int2(src[e], e);
    }
}

// ------------------------------------------------- xl = x@Wl+bl, xr = x@Wr
#define GROWS 32
__global__ __launch_bounds__(256) void gemm2_kernel(const float* __restrict__ xin, int K,
                                                    const float* __restrict__ Wl,
                                                    const float* __restrict__ bl,
                                                    const float* __restrict__ Wr,
                                                    float* __restrict__ xl,
                                                    float* __restrict__ xr, int Nn) {
    __shared__ __align__(16) float sh[GROWS][64];
    int j = threadIdx.x;  // output column 0..255
    int n0 = blockIdx.x * GROWS;
    for (int t = threadIdx.x; t < GROWS * K; t += 256) {
        int r = t / K, k = t - r * K;
        int n = n0 + r;
        sh[r][k] = (n < Nn) ? xin[(size_t)n * K + k] : 0.f;
    }
    __syncthreads();
    float accl[GROWS], accr[GROWS];
    float b = bl[j];
#pragma unroll
    for (int r = 0; r < GROWS; r++) { accl[r] = b; accr[r] = 0.f; }
    if (K == 64) {
        for (int k4 = 0; k4 < 16; k4++) {
            int k = k4 * 4;
            float wl0 = Wl[(k + 0) * 256 + j], wl1 = Wl[(k + 1) * 256 + j];
            float wl2 = Wl[(k + 2) * 256 + j], wl3 = Wl[(k + 3) * 256 + j];
            float wr0 = Wr[(k + 0) * 256 + j], wr1 = Wr[(k + 1) * 256 + j];
            float wr2 = Wr[(k + 2) * 256 + j], wr3 = Wr[(k + 3) * 256 + j];
#pragma unroll
            for (int r = 0; r < GROWS; r++) {
                float4 h4 = *(const float4*)&sh[r][k];
                accl[r] += h4.x * wl0 + h4.y * wl1 + h4.z * wl2 + h4.w * wl3;
                accr[r] += h4.x * wr0 + h4.y * wr1 + h4.z * wr2 + h4.w * wr3;
            }
        }
    } else {
        for (int k = 0; k < K; k++) {
            float wl = Wl[k * 256 + j], wr = Wr[k * 256 + j];
#pragma unroll
            for (int r = 0; r < GROWS; r++) { accl[r] += sh[r][k] * wl; accr[r] += sh[r][k] * wr; }
        }
    }
    for (int r = 0; r < GROWS; r++) {
        int n = n0 + r;
        if (n < Nn) { xl[(size_t)n * 256 + j] = accl[r]; xr[(size_t)n * 256 + j] = accr[r]; }
    }
}

// --------------------------- fused GATv2: wave-per-node, 4 channels/lane.
// lane = h*16 + cg holds channels cg*4..cg*4+3 of head h (flat cf = lane*4+j).
// Score reduce = 16-lane shuffle; online softmax per 16-lane head group.
#define EB 8
__global__ __launch_bounds__(256) void gat_kernel(const float* __restrict__ xl,
                                                  const float* __restrict__ xr,
                                                  const float* __restrict__ We,   // [3,256]
                                                  const float* __restrict__ att,  // [256]
                                                  const float* __restrict__ bias, // [64]
                                                  const float* __restrict__ bng,
                                                  const float* __restrict__ bnb,
                                                  const float* __restrict__ bnm,
                                                  const float* __restrict__ bnv,
                                                  const float* __restrict__ ea,   // [E,3]
                                                  const int* __restrict__ rowptr,
                                                  const int2* __restrict__ csr,
                                                  float* __restrict__ hout,       // [N,64]
                                                  const float* __restrict__ hres, // [N,64] or null
                                                  int Nn) {
    int tid = threadIdx.x;
    int w = tid >> 6, lane = tid & 63;
    int d = blockIdx.x * 4 + w;
    if (d >= Nn) return;

    float4 we0 = *(const float4*)&We[lane * 4];
    float4 we1 = *(const float4*)&We[256 + lane * 4];
    float4 we2 = *(const float4*)&We[512 + lane * 4];
    float4 attv = *(const float4*)&att[lane * 4];
    float4 xrv = *(const float4*)&xr[(size_t)d * 256 + lane * 4];
    int beg = rowptr[d], end = rowptr[d + 1];

    float m_run = -INFINITY, l_run = 0.f;
    float4 acc = make_float4(0.f, 0.f, 0.f, 0.f);

    for (int i0 = beg; i0 < end; i0 += EB) {
        float4 xlv[EB];
        float p[EB];
#pragma unroll
        for (int j = 0; j < EB; j++) {
            int idx = i0 + j;
            if (idx < end) {
                int2 se = csr[idx];
                size_t eb3 = (size_t)se.y * 3;
                float ea0 = ea[eb3], ea1 = ea[eb3 + 1], ea2 = ea[eb3 + 2];
                xlv[j] = *(const float4*)&xl[(size_t)se.x * 256 + lane * 4];
                float tx = fmaf(ea0, we0.x, fmaf(ea1, we1.x, fmaf(ea2, we2.x, xrv.x))) + xlv[j].x;
                float ty = fmaf(ea0, we0.y, fmaf(ea1, we1.y, fmaf(ea2, we2.y, xrv.y))) + xlv[j].y;
                float tz = fmaf(ea0, we0.z, fmaf(ea1, we1.z, fmaf(ea2, we2.z, xrv.z))) + xlv[j].z;
                float tw = fmaf(ea0, we0.w, fmaf(ea1, we1.w, fmaf(ea2, we2.w, xrv.w))) + xlv[j].w;
                float pp;
                pp = (tx > 0.f ? tx : 0.2f * tx) * attv.x;
                pp = fmaf((ty > 0.f ? ty : 0.2f * ty), attv.y, pp);
                pp = fmaf((tz > 0.f ? tz : 0.2f * tz), attv.z, pp);
                pp = fmaf((tw > 0.f ? tw : 0.2f * tw), attv.w, pp);
                p[j] = pp;
            } else {
                p[j] = -INFINITY;
                xlv[j] = make_float4(0.f, 0.f, 0.f, 0.f);
            }
        }
        // 16-lane reduce within each head group
#pragma unroll
        for (int off = 1; off < 16; off <<= 1) {
#pragma unroll
            for (int j = 0; j < EB; j++) p[j] += __shfl_xor(p[j], off);
        }
        // online softmax update (deferred max, wave-voted)
#pragma unroll
        for (int j = 0; j < EB; j++) {
            if (__all(p[j] <= m_run)) {
                float wv = __expf(p[j] - m_run);
                acc.x = fmaf(wv, xlv[j].x, acc.x);
                acc.y = fmaf(wv, xlv[j].y, acc.y);
                acc.z = fmaf(wv, xlv[j].z, acc.z);
                acc.w = fmaf(wv, xlv[j].w, acc.w);
                l_run += wv;
            } else {
                float mnew = fmaxf(m_run, p[j]);
                float sc = __expf(m_run - mnew);   // 0 when m_run==-inf
                float wv = __expf(p[j] - mnew);
                acc.x = fmaf(acc.x, sc, wv * xlv[j].x);
                acc.y = fmaf(acc.y, sc, wv * xlv[j].y);
                acc.z = fmaf(acc.z, sc, wv * xlv[j].z);
                acc.w = fmaf(acc.w, sc, wv * xlv[j].w);
                l_run = fmaf(l_run, sc, wv);
                m_run = mnew;
            }
        }
    }
    float inv = (end > beg) ? 1.f / l_run : 0.f;
    float4 outv = make_float4(acc.x * inv, acc.y * inv, acc.z * inv, acc.w * inv);
    // mean over heads: sum lanes {lane&15 + 16h}
#pragma unroll
    for (int off = 16; off < 64; off <<= 1) {
        outv.x += __shfl_xor(outv.x, off);
        outv.y += __shfl_xor(outv.y, off);
        outv.z += __shfl_xor(outv.z, off);
        outv.w += __shfl_xor(outv.w, off);
    }
    if (lane < 16) {
        int c0 = lane * 4;
        float4 b4 = *(const float4*)&bias[c0];
        float4 g4 = *(const float4*)&bng[c0];
        float4 bb4 = *(const float4*)&bnb[c0];
        float4 m4 = *(const float4*)&bnm[c0];
        float4 v4 = *(const float4*)&bnv[c0];
        float vx = 0.25f * outv.x + b4.x, vy = 0.25f * outv.y + b4.y;
        float vz = 0.25f * outv.z + b4.z, vw = 0.25f * outv.w + b4.w;
        vx = (vx - m4.x) * (g4.x * rsqrtf(v4.x + 1e-5f)) + bb4.x;
        vy = (vy - m4.y) * (g4.y * rsqrtf(v4.y + 1e-5f)) + bb4.y;
        vz = (vz - m4.z) * (g4.z * rsqrtf(v4.z + 1e-5f)) + bb4.z;
        vw = (vw - m4.w) * (g4.w * rsqrtf(v4.w + 1e-5f)) + bb4.w;
        vx = vx > 0.f ? vx : expm1f(vx);
        vy = vy > 0.f ? vy : expm1f(vy);
        vz = vz > 0.f ? vz : expm1f(vz);
        vw = vw > 0.f ? vw : expm1f(vw);
        if (hres) {
            float4 r4 = *(const float4*)&hres[(size_t)d * 64 + c0];
            vx += r4.x; vy += r4.y; vz += r4.z; vw += r4.w;
        }
        *(float4*)&hout[(size_t)d * 64 + c0] = make_float4(vx, vy, vz, vw);
    }
}

// ---------------------------------------------------------------- pooling
__global__ __launch_bounds__(256) void pool_kernel(const float* __restrict__ h,
                                                   const int* __restrict__ batch,
                                                   float* __restrict__ pooled,
                                                   int* __restrict__ cnt, int Nn) {
    int idx = blockIdx.x * 256 + threadIdx.x;
    int n = idx >> 6, c = idx & 63;
    if (n < Nn) {
        int g = batch[n];
        atomicAdd(&pooled[(size_t)g * 64 + c], h[(size_t)n * 64 + c]);
        if (c == 0) atomicAdd(&cnt[g], 1);
    }
}

// ---------------------------------------------------------------- MLP head
__global__ __launch_bounds__(64) void head_kernel(const float* __restrict__ pooled,
                                                  const int* __restrict__ cnt,
                                                  const float* __restrict__ Wo1,
                                                  const float* __restrict__ bo1,
                                                  const float* __restrict__ Wo2,
                                                  const float* __restrict__ bo2,
                                                  float* __restrict__ out, int Gg) {
    int g = blockIdx.x;
    int t = threadIdx.x;
    __shared__ float sp[64];
    float c = fmaxf((float)cnt[g], 1.f);
    sp[t] = pooled[(size_t)g * 64 + t] / c;
    __syncthreads();
    float hid = 0.f;
    if (t < 32) {
        hid = bo1[t];
        for (int k = 0; k < 64; k++) hid += sp[k] * Wo1[k * 32 + t];
        hid = hid > 0.f ? hid : expm1f(hid);
        hid *= Wo2[t];
    }
#pragma unroll
    for (int off = 32; off; off >>= 1) hid += __shfl_xor(hid, off);
    if (t == 0) out[g] = hid + bo2[0];
}

extern "C" void kernel_launch(void* const* d_in, const int* in_sizes, int n_in,
                              void* d_out, int out_size, void* d_ws, size_t ws_size,
                              hipStream_t stream) {
    const float* x   = (const float*)d_in[0];
    const int*   ei  = (const int*)d_in[1];
    const int*   bat = (const int*)d_in[2];
    const float* ea  = (const float*)d_in[3];
    const float* W0l = (const float*)d_in[4];
    const float* b0l = (const float*)d_in[5];
    const float* W0r = (const float*)d_in[6];
    const float* W0e = (const float*)d_in[7];
    const float* a0  = (const float*)d_in[8];
    const float* c0  = (const float*)d_in[9];
    const float* Wl  = (const float*)d_in[10];
    const float* bl  = (const float*)d_in[11];
    const float* Wr  = (const float*)d_in[12];
    const float* We  = (const float*)d_in[13];
    const float* a   = (const float*)d_in[14];
    const float* cb  = (const float*)d_in[15];
    const float* bng = (const float*)d_in[16];
    const float* bnb = (const float*)d_in[17];
    const float* bnm = (const float*)d_in[18];
    const float* bnv = (const float*)d_in[19];
    const float* Wo1 = (const float*)d_in[20];
    const float* bo1 = (const float*)d_in[21];
    const float* Wo2 = (const float*)d_in[22];
    const float* bo2 = (const float*)d_in[23];

    int Nn = in_sizes[2];
    int Ee = in_sizes[1] / 2;
    int Gg = out_size;
    const int* srcv = ei;
    const int* dstv = ei + Ee;

    char* w = (char*)d_ws;
    auto alloc = [&](size_t bytes) {
        char* p = w;
        w += (bytes + 255) & ~(size_t)255;
        return p;
    };
    float* xlb    = (float*)alloc((size_t)Nn * 256 * 4);
    float* xrb    = (float*)alloc((size_t)Nn * 256 * 4);
    float* hbuf   = (float*)alloc((size_t)Nn * 64 * 4);
    int*   deg    = (int*)alloc((size_t)Nn * 4);
    int*   rowptr = (int*)alloc((size_t)(Nn + 1) * 4);
    int*   cursor = (int*)alloc((size_t)Nn * 4);
    int2*  csr    = (int2*)alloc((size_t)Ee * 8);
    float* pooled = (float*)alloc((size_t)Gg * 64 * 4);
    int*   cnt    = (int*)alloc((size_t)Gg * 4);
    int*   bsum   = (int*)alloc(256 * 4);

    int nscan = (Nn + SCAN_ELEMS - 1) / SCAN_ELEMS;  // <=256 for Nn<=262144

    // CSR build
    hipMemsetAsync(deg, 0, (size_t)Nn * 4, stream);
    count_kernel<<<(Ee + 255) / 256, 256, 0, stream>>>(dstv, deg, Ee);
    scan_phase1<<<nscan, 256, 0, stream>>>(deg, bsum, Nn);
    scan_phase2<<<1, 256, 0, stream>>>(bsum, nscan, rowptr, Nn);
    scan_phase3<<<nscan, 256, 0, stream>>>(deg, bsum, rowptr, cursor, Nn);
    scatter_kernel<<<(Ee + 255) / 256, 256, 0, stream>>>(srcv, dstv, cursor, csr, Ee);

    int gatg = (Nn + 3) / 4;

    // layer 0 (K=9)
    gemm2_kernel<<<(Nn + GROWS - 1) / GROWS, 256, 0, stream>>>(x, 9, W0l, b0l, W0r, xlb, xrb, Nn);
    gat_kernel<<<gatg, 256, 0, stream>>>(xlb, xrb, W0e, a0, c0,
                                         bng, bnb, bnm, bnv,
                                         ea, rowptr, csr, hbuf, nullptr, Nn);
    // 3 residual layers (K=64)
    for (int i = 0; i < 3; i++) {
        gemm2_kernel<<<(Nn + GROWS - 1) / GROWS, 256, 0, stream>>>(
            hbuf, 64, Wl + (size_t)i * 64 * 256, bl + (size_t)i * 256,
            Wr + (size_t)i * 64 * 256, xlb, xrb, Nn);
        gat_kernel<<<gatg, 256, 0, stream>>>(
            xlb, xrb, We + (size_t)i * 768, a + (size_t)i * 256, cb + (size_t)i * 64,
            bng + (size_t)(i + 1) * 64, bnb + (size_t)(i + 1) * 64,
            bnm + (size_t)(i + 1) * 64, bnv + (size_t)(i + 1) * 64,
            ea, rowptr, csr, hbuf, hbuf, Nn);
    }

    // global mean pool + head
    hipMemsetAsync(pooled, 0, (size_t)Gg * 64 * 4, stream);
    hipMemsetAsync(cnt, 0, (size_t)Gg * 4, stream);
    pool_kernel<<<((size_t)Nn * 64 + 255) / 256, 256, 0, stream>>>(hbuf, bat, pooled, cnt, Nn);
    head_kernel<<<Gg, 64, 0, stream>>>(pooled, cnt, Wo1, bo1, Wo2, bo2, (float*)d_out, Gg);
}